// Round 7
// baseline (234.074 us; speedup 1.0000x reference)
//
#include <hip/hip_runtime.h>
#include <hip/hip_bf16.h>
#include <cstdint>
#include <cstddef>

// ---------------------------------------------------------------------------
// SelfAttention pipeline R7:
//   1. cvt4: fp32->bf16 for x, Wq, Wk, Wv (one dispatch)
//   2. gemm_qkv8: 256x256x64 8-phase pipelined GEMM (m201-class schedule),
//      A=xb[2048x2048], B=[Wq|Wk|Wv][6144x2048] packed, counted vmcnt(6),
//      raw s_barriers, 1 half-tile staged per phase. Epilogue: z<2 ->
//      qT,kT transposed [m][l]; z=2 -> v[bc][m]; bias direct from d_in.
//   3. flash3: 512 blocks x 4 waves, 32 q-rows/wave, no-max exp2 softmax,
//      ones-MFMA row sums, XOR-swizzled K/V LDS, partials po fp16/pl fp32.
//   4. combine4: out[b,c,l] = sum_sg po / sum_sg pl
// ---------------------------------------------------------------------------

typedef __bf16 bf16_t;
typedef _Float16 fp16_t;
typedef __bf16 bf16x8 __attribute__((ext_vector_type(8)));
typedef __bf16 bf16x4 __attribute__((ext_vector_type(4)));
typedef float floatx4 __attribute__((ext_vector_type(4)));

#define GLD_LDS16(gptr, lptr)                                                  \
  __builtin_amdgcn_global_load_lds(                                            \
      (const __attribute__((address_space(1))) void*)(gptr),                   \
      (__attribute__((address_space(3))) void*)(lptr), 16, 0, 0)

// raw barrier with compile-time pins (no vmcnt(0) drain, no reordering)
#define BARRAW()                                                               \
  do {                                                                         \
    __builtin_amdgcn_sched_barrier(0);                                         \
    asm volatile("" ::: "memory");                                             \
    __builtin_amdgcn_s_barrier();                                              \
    __builtin_amdgcn_sched_barrier(0);                                         \
  } while (0)

// ---------------- fp32 -> bf16 conversion, 4 matrices in one dispatch -------
__global__ __launch_bounds__(256) void cvt4_f32_bf16(
    const float* __restrict__ s0, const float* __restrict__ s1,
    const float* __restrict__ s2, const float* __restrict__ s3,
    bf16_t* __restrict__ d0, bf16_t* __restrict__ d1,
    bf16_t* __restrict__ d2, bf16_t* __restrict__ d3) {
  const float* s;
  bf16_t* d;
  switch (blockIdx.y) {
    case 0: s = s0; d = d0; break;
    case 1: s = s1; d = d1; break;
    case 2: s = s2; d = d2; break;
    default: s = s3; d = d3; break;
  }
  const int i = (blockIdx.x * 256 + threadIdx.x) * 4;
  const float4 v = *reinterpret_cast<const float4*>(s + i);
  bf16x4 o;
  o[0] = (bf16_t)v.x; o[1] = (bf16_t)v.y; o[2] = (bf16_t)v.z; o[3] = (bf16_t)v.w;
  *reinterpret_cast<bf16x4*>(d + i) = o;
}

// ---------------- 256x256 8-phase QKV GEMM ----------------------------------
// C[i,j] = sum_k A[i,k]*B[j,k]; A=xb [2048][2048], B=Wp [6144][2048].
// 192 blocks x 512 thr (8 waves 2Mx4N). BK=64. LDS 128KB: As/Bs[2 buf] each
// [2 kk-half][256 rows][32 cols]. Stage stream: half-tile ht=4*tile+part,
// part={0:B-k0, 1:A-k0, 2:B-k1, 3:A-k1}; in-loop phase p stages ht=8j+6+p.
// Each region staged exactly one phase after its last LDS reader.
__global__ __launch_bounds__(512, 2) void gemm_qkv8(
    const bf16_t* __restrict__ xb, const bf16_t* __restrict__ Wp,
    bf16_t* __restrict__ tT, bf16_t* __restrict__ vb,
    const float* __restrict__ bq, const float* __restrict__ bk,
    const float* __restrict__ bv) {
  __shared__ __align__(16) bf16_t As[2 * 16384];
  __shared__ __align__(16) bf16_t Bs[2 * 16384];

  constexpr long M4 = 4l * 1024 * 1024;
  const int tid = threadIdx.x, lane = tid & 63, w = tid >> 6;
  const int i15 = lane & 15, g4 = lane >> 4;
  const int wm = w >> 2, wn = w & 3;

  // XCD-bijective swizzle (192 % 8 == 0)
  const int o = blockIdx.x;
  const int swz = (o & 7) * 24 + (o >> 3);
  const int mx = swz & 7, nx = swz >> 3;
  const int brow = mx * 256, bcol = nx * 256;

  // staging: per call 512thr x 16B = 8KB = 128 rows x 64B; row=tid>>2, slot=tid&3
  const int srow = tid >> 2, sslot = tid & 3;
  const bf16_t* Ag = xb + (size_t)(brow + srow) * 2048 + sslot * 8;
  const bf16_t* Bg = Wp + (size_t)(bcol + srow) * 2048 + sslot * 8;

  auto stage_ht = [&](int h) {
    const int tile = h >> 2, buf = tile & 1, part = h & 3;
    const int kk = part >> 1;
    const bool isA = part & 1;
    const bf16_t* g = (isA ? Ag : Bg) + tile * 64 + kk * 32;
    bf16_t* l = (isA ? As : Bs) + buf * 16384 + kk * 8192 + w * 512;
    GLD_LDS16(g, l);
    GLD_LDS16(g + (size_t)128 * 2048, l + 4096);
  };

  floatx4 acc[8][4];
#pragma unroll
  for (int m = 0; m < 8; m++)
#pragma unroll
    for (int n = 0; n < 4; n++) acc[m][n] = (floatx4)0.f;

  bf16x8 Ar[4], Br[4];

#define LDA(buf, kk, mh)                                                       \
  {                                                                            \
    const bf16_t* ab = As + (buf) * 16384 + (kk) * 8192 +                      \
                       (wm * 128 + (mh) * 64 + i15) * 32 + g4 * 8;             \
    Ar[0] = *(const bf16x8*)&ab[0 * 512];                                      \
    Ar[1] = *(const bf16x8*)&ab[1 * 512];                                      \
    Ar[2] = *(const bf16x8*)&ab[2 * 512];                                      \
    Ar[3] = *(const bf16x8*)&ab[3 * 512];                                      \
  }
#define LDB(buf, kk)                                                           \
  {                                                                            \
    const bf16_t* bb = Bs + (buf) * 16384 + (kk) * 8192 +                      \
                       (wn * 64 + i15) * 32 + g4 * 8;                          \
    Br[0] = *(const bf16x8*)&bb[0 * 512];                                      \
    Br[1] = *(const bf16x8*)&bb[1 * 512];                                      \
    Br[2] = *(const bf16x8*)&bb[2 * 512];                                      \
    Br[3] = *(const bf16x8*)&bb[3 * 512];                                      \
  }
#define MMA(mh)                                                                \
  {                                                                            \
    __builtin_amdgcn_s_setprio(1);                                             \
    _Pragma("unroll") for (int mf = 0; mf < 4; mf++)                           \
        _Pragma("unroll") for (int nf = 0; nf < 4; nf++)                       \
        acc[(mh) * 4 + mf][nf] = __builtin_amdgcn_mfma_f32_16x16x32_bf16(      \
            Ar[mf], Br[nf], acc[(mh) * 4 + mf][nf], 0, 0, 0);                  \
    __builtin_amdgcn_s_setprio(0);                                             \
  }

  // prologue: tile0 (HT0-3) + 3 half-tiles of tile1
  for (int h = 0; h < 7; ++h) stage_ht(h);
  asm volatile("s_waitcnt vmcnt(6)" ::: "memory");
  BARRAW();

  for (int j = 0; j < 16; ++j) {
    const int hb = 8 * j + 6;
    // ---- phases 1-4: tile 2j (buf0) ----
    LDB(0, 0); LDA(0, 0, 0);
    stage_ht(hb + 1); BARRAW(); MMA(0); BARRAW();                     // p1
    LDA(0, 0, 1);
    if (hb + 2 < 128) stage_ht(hb + 2); BARRAW(); MMA(1); BARRAW();   // p2
    LDB(0, 1); LDA(0, 1, 0);
    if (hb + 3 < 128) stage_ht(hb + 3); BARRAW(); MMA(0);             // p3
    BARRAW();
    LDA(0, 1, 1);
    if (hb + 4 < 128) stage_ht(hb + 4); BARRAW(); MMA(1);             // p4
    __builtin_amdgcn_sched_barrier(0);
    if (j == 15)
      asm volatile("s_waitcnt vmcnt(0)" ::: "memory");
    else
      asm volatile("s_waitcnt vmcnt(6)" ::: "memory");
    BARRAW();
    // ---- phases 5-8: tile 2j+1 (buf1) ----
    LDB(1, 0); LDA(1, 0, 0);
    if (hb + 5 < 128) stage_ht(hb + 5); BARRAW(); MMA(0); BARRAW();   // p5
    LDA(1, 0, 1);
    if (hb + 6 < 128) stage_ht(hb + 6); BARRAW(); MMA(1); BARRAW();   // p6
    LDB(1, 1); LDA(1, 1, 0);
    if (hb + 7 < 128) stage_ht(hb + 7); BARRAW(); MMA(0); BARRAW();   // p7
    LDA(1, 1, 1);
    if (hb + 8 < 128) stage_ht(hb + 8); BARRAW(); MMA(1);             // p8
    __builtin_amdgcn_sched_barrier(0);
    if (j < 15) asm volatile("s_waitcnt vmcnt(6)" ::: "memory");
    BARRAW();
  }
#undef LDA
#undef LDB
#undef MMA

  // ---- epilogue: z<2 -> transposed qT/kT; z=2 -> v ------------------------
#pragma unroll
  for (int nf = 0; nf < 4; nf++) {
    const int gj = bcol + wn * 64 + nf * 16 + i15;
    const int z = gj >> 11, jj = gj & 2047;
    const float* bp = (z == 0) ? bq : (z == 1) ? bk : bv;
    const float badd = bp[jj];
#pragma unroll
    for (int mf = 0; mf < 8; mf++) {
      const int gi = brow + wm * 128 + mf * 16 + g4 * 4;
      if (z < 2) {
        bf16x4 ov;
#pragma unroll
        for (int r = 0; r < 4; r++) ov[r] = (bf16_t)(acc[mf][nf][r] + badd);
        *(bf16x4*)&tT[(size_t)z * M4 + (size_t)jj * 2048 + gi] = ov;
      } else {
#pragma unroll
        for (int r = 0; r < 4; r++)
          vb[(size_t)(gi + r) * 2048 + jj] = (bf16_t)(acc[mf][nf][r] + badd);
      }
    }
  }
}

// ---------------- flash3: no-max segmented attention, 32 rows/wave -----------
__global__ __launch_bounds__(256, 2) void flash3(
    const bf16_t* __restrict__ qT, const bf16_t* __restrict__ kT,
    const bf16_t* __restrict__ v, fp16_t* __restrict__ po,
    float* __restrict__ pl) {
  __shared__ __align__(16) bf16_t Ks[8192];      // [8 ks][32 m][32 c] 16 KB
  __shared__ __align__(16) bf16_t Vs[8192];      // [256 c][32 m]      16 KB
  __shared__ __align__(16) bf16_t Ps[4 * 1280];  // [w][32 l][40 m]    10 KB

  const int tid = threadIdx.x, lane = tid & 63, w = tid >> 6;
  const int idx = blockIdx.x;
  const int b = idx & 7, sg = (idx >> 3) & 3, qt = idx >> 5;
  const int l0 = qt * 128;
  const int key0 = sg * 512;
  const int i15 = lane & 15, g4 = lane >> 4;

  const bf16_t* Qg = qT + (size_t)(l0 + w * 32) * 2048 + b * 256;
  const bf16_t* Kg = kT + (size_t)key0 * 2048 + b * 256;
  const bf16_t* Vg = v + (size_t)b * 256 * 2048 + key0;

  bf16x8 af0[8], af1[8];
#pragma unroll
  for (int ks = 0; ks < 8; ks++) {
    af0[ks] = *(const bf16x8*)&Qg[(size_t)i15 * 2048 + ks * 32 + g4 * 8];
    af1[ks] = *(const bf16x8*)&Qg[(size_t)(16 + i15) * 2048 + ks * 32 + g4 * 8];
  }

  const int srow = lane >> 2;
  const int sslot = (lane & 3) ^ ((lane >> 3) & 3);
  auto stageK = [&](const bf16_t* g) {
#pragma unroll
    for (int j = 0; j < 4; j++) {
      const int ch = w * 4 + j, ks = ch >> 1, mseg = ch & 1;
      GLD_LDS16(g + (size_t)(mseg * 16 + srow) * 2048 + ks * 32 + sslot * 8,
                Ks + ch * 512);
    }
  };
  auto stageV = [&](const bf16_t* g) {
#pragma unroll
    for (int j = 0; j < 4; j++) {
      const int ch = w * 4 + j;
      GLD_LDS16(g + (size_t)(ch * 16 + srow) * 2048 + sslot * 8, Vs + ch * 512);
    }
  };

  floatx4 acc_o0[16], acc_o1[16];
#pragma unroll
  for (int cf = 0; cf < 16; cf++) {
    acc_o0[cf] = (floatx4)0.f;
    acc_o1[cf] = (floatx4)0.f;
  }
  floatx4 acc_l0 = (floatx4)0.f, acc_l1 = (floatx4)0.f;

  bf16x8 vones;
#pragma unroll
  for (int j = 0; j < 8; j++) vones[j] = (bf16_t)1.0f;

  const float SC = 0.031880107f;            // (1/sqrt(2048)) * log2(e)
  const int slotr = g4 ^ ((i15 >> 1) & 3);  // swizzled read slot

  stageK(Kg);
  stageV(Vg);
  __syncthreads();

  for (int t = 0; t < 16; t++) {
    floatx4 s00 = (floatx4)0.f, s01 = (floatx4)0.f;
    floatx4 s10 = (floatx4)0.f, s11 = (floatx4)0.f;
#pragma unroll
    for (int ks = 0; ks < 8; ks++) {
      const bf16x8 b0 = *(const bf16x8*)&Ks[ks * 1024 + i15 * 32 + slotr * 8];
      const bf16x8 b1 =
          *(const bf16x8*)&Ks[ks * 1024 + (16 + i15) * 32 + slotr * 8];
      s00 = __builtin_amdgcn_mfma_f32_16x16x32_bf16(af0[ks], b0, s00, 0, 0, 0);
      s01 = __builtin_amdgcn_mfma_f32_16x16x32_bf16(af0[ks], b1, s01, 0, 0, 0);
      s10 = __builtin_amdgcn_mfma_f32_16x16x32_bf16(af1[ks], b0, s10, 0, 0, 0);
      s11 = __builtin_amdgcn_mfma_f32_16x16x32_bf16(af1[ks], b1, s11, 0, 0, 0);
    }
    __syncthreads();
    if (t < 15) stageK(Kg + (size_t)(t + 1) * 32 * 2048);

    bf16_t* Pw = Ps + w * 1280;
#pragma unroll
    for (int r = 0; r < 4; r++) {
      Pw[(g4 * 4 + r) * 40 + i15] = (bf16_t)exp2f(s00[r] * SC);
      Pw[(g4 * 4 + r) * 40 + 16 + i15] = (bf16_t)exp2f(s01[r] * SC);
      Pw[(16 + g4 * 4 + r) * 40 + i15] = (bf16_t)exp2f(s10[r] * SC);
      Pw[(16 + g4 * 4 + r) * 40 + 16 + i15] = (bf16_t)exp2f(s11[r] * SC);
    }
    const bf16x8 pa0 = *(const bf16x8*)&Pw[i15 * 40 + g4 * 8];
    const bf16x8 pa1 = *(const bf16x8*)&Pw[(16 + i15) * 40 + g4 * 8];
    acc_l0 = __builtin_amdgcn_mfma_f32_16x16x32_bf16(pa0, vones, acc_l0, 0, 0, 0);
    acc_l1 = __builtin_amdgcn_mfma_f32_16x16x32_bf16(pa1, vones, acc_l1, 0, 0, 0);
#pragma unroll
    for (int cf = 0; cf < 16; cf++) {
      const bf16x8 bv = *(const bf16x8*)&Vs[(cf * 16 + i15) * 32 + slotr * 8];
      acc_o0[cf] = __builtin_amdgcn_mfma_f32_16x16x32_bf16(pa0, bv, acc_o0[cf], 0, 0, 0);
      acc_o1[cf] = __builtin_amdgcn_mfma_f32_16x16x32_bf16(pa1, bv, acc_o1[cf], 0, 0, 0);
    }
    __syncthreads();
    if (t < 15) stageV(Vg + (t + 1) * 32);
  }

  fp16_t* pob = po + ((size_t)(b * 4 + sg) * 2048 + l0 + w * 32) * 256;
#pragma unroll
  for (int cf = 0; cf < 16; cf++)
#pragma unroll
    for (int r = 0; r < 4; r++) {
      pob[(size_t)(g4 * 4 + r) * 256 + cf * 16 + i15] = (fp16_t)acc_o0[cf][r];
      pob[(size_t)(16 + g4 * 4 + r) * 256 + cf * 16 + i15] =
          (fp16_t)acc_o1[cf][r];
    }
  if (i15 == 0) {
    float* plb = pl + (size_t)(b * 4 + sg) * 2048 + l0 + w * 32;
#pragma unroll
    for (int r = 0; r < 4; r++) {
      plb[g4 * 4 + r] = acc_l0[r];
      plb[16 + g4 * 4 + r] = acc_l1[r];
    }
  }
}

// ---------------- combine 4 segments -> out[b,c,l] fp32 ----------------------
__global__ __launch_bounds__(256) void combine4(
    const fp16_t* __restrict__ po, const float* __restrict__ pl,
    float* __restrict__ out) {
  __shared__ float invd[32];
  __shared__ float tile[32][33];
  const int lt = blockIdx.x, ct = blockIdx.y, b = blockIdx.z;
  const int l0 = lt * 32, c0 = ct * 32;
  const int t = threadIdx.x;

  if (t < 32) {
    float d = 0.f;
#pragma unroll
    for (int s = 0; s < 4; s++) d += pl[(size_t)(b * 4 + s) * 2048 + l0 + t];
    invd[t] = 1.f / d;
  }
  __syncthreads();

  const int c = t & 31;
#pragma unroll
  for (int pass = 0; pass < 4; pass++) {
    const int l = pass * 8 + (t >> 5);
    float acc = 0.f;
#pragma unroll
    for (int s = 0; s < 4; s++)
      acc += (float)po[((size_t)(b * 4 + s) * 2048 + l0 + l) * 256 + c0 + c];
    tile[c][l] = acc * invd[l];
  }
  __syncthreads();

  const int oc = t >> 3, lw = (t & 7) * 4;
  float4 val = {tile[oc][lw], tile[oc][lw + 1], tile[oc][lw + 2], tile[oc][lw + 3]};
  *(float4*)&out[((size_t)b * 256 + c0 + oc) * 2048 + l0 + lw] = val;
}

// ---------------------------------------------------------------------------
extern "C" void kernel_launch(void* const* d_in, const int* in_sizes, int n_in,
                              void* d_out, int out_size, void* d_ws,
                              size_t ws_size, hipStream_t stream) {
  const float* x = (const float*)d_in[0];
  float* out = (float*)d_out;

  constexpr long M4 = 4l * 1024 * 1024;
  bf16_t* ws = (bf16_t*)d_ws;
  bf16_t* xb = ws;            // [bc, l]        8 MB
  bf16_t* Wb = ws + M4;       // Wq,Wk,Wv packed [6144][2048]  24 MB
  bf16_t* tT = ws + 4 * M4;   // qT,kT [m, bc]  16 MB
  bf16_t* vb = ws + 6 * M4;   // v [bc, m]      8 MB
  fp16_t* po = (fp16_t*)(ws + 7 * M4);   // [8][4][2048][256] fp16, 33.5 MB
  float* pl = (float*)(po + 8l * 4 * 2048 * 256);  // [8][4][2048] fp32

  cvt4_f32_bf16<<<dim3(4096, 4), 256, 0, stream>>>(
      x, (const float*)d_in[1], (const float*)d_in[3], (const float*)d_in[5],
      xb, Wb, Wb + M4, Wb + 2 * M4);

  // qT,kT (transposed write) + v; 8-phase 256^2 pipeline
  gemm_qkv8<<<dim3(192), 512, 0, stream>>>(
      xb, Wb, tT, vb, (const float*)d_in[2], (const float*)d_in[4],
      (const float*)d_in[6]);

  // segmented no-max flash attention -> partials
  flash3<<<dim3(512), 256, 0, stream>>>(tT, tT + M4, vb, po, pl);

  // merge segments -> out
  combine4<<<dim3(64, 8, 8), 256, 0, stream>>>(po, pl, out);
}